// Round 1
// baseline (413.082 us; speedup 1.0000x reference)
//
#include <hip/hip_runtime.h>
#include <cstdint>

// ---- types ----
typedef __bf16  bf16;
typedef __bf16  bf16x8 __attribute__((ext_vector_type(8)));
typedef __bf16  bf16x4 __attribute__((ext_vector_type(4)));
typedef __bf16  bf16x2 __attribute__((ext_vector_type(2)));
typedef float   f32x4  __attribute__((ext_vector_type(4)));
typedef float   f32x16 __attribute__((ext_vector_type(16)));

#define GLOAD_LDS16(g, l) __builtin_amdgcn_global_load_lds( \
    (const __attribute__((address_space(1))) void*)(g),     \
    (__attribute__((address_space(3))) void*)(l), 16, 0, 0)

// dims
#define SEQ   2048
#define HID   2048
#define NH    16
#define NKV   8
#define HD    128
#define NQKV  6144   // 4096 q_all + 1024 k + 1024 v
#define MTOT  4096   // B*SEQ

// ---------------- fused prep: convx + all weight transposes ----------------
__device__ __forceinline__ void transw_body(const float* __restrict__ W, bf16* __restrict__ WT,
                                            int N, int n0, int k0, int t) {
    __shared__ float tile[64][65];
    int tn = t & 63, t4 = t >> 6;
    #pragma unroll
    for (int i = 0; i < 16; ++i) {
        int kk = i * 4 + t4;
        tile[kk][tn] = W[(size_t)(k0 + kk) * N + n0 + tn];
    }
    __syncthreads();
    #pragma unroll
    for (int i = 0; i < 16; ++i) {
        int nn = i * 4 + t4;
        WT[(size_t)(n0 + nn) * HID + k0 + tn] = (bf16)tile[tn][nn];
    }
}

__global__ __launch_bounds__(256) void prep_kernel(const float* __restrict__ x, bf16* __restrict__ xb,
                                                   const float* __restrict__ Wq, const float* __restrict__ Wk,
                                                   const float* __restrict__ Wv, const float* __restrict__ Wo,
                                                   bf16* __restrict__ wqkvT, bf16* __restrict__ woT) {
    int bx = blockIdx.x, t = threadIdx.x;
    if (bx < 8192) {                                   // convx: 4 f32->bf16 per thread
        int i = bx * 256 + t;
        f32x4 v = ((const f32x4*)x)[i];
        bf16x4 o;
        o[0] = (bf16)v[0]; o[1] = (bf16)v[1]; o[2] = (bf16)v[2]; o[3] = (bf16)v[3];
        ((bf16x4*)xb)[i] = o;
    } else if (bx < 8192 + 2048) {                     // Wq: N=4096
        int idx = bx - 8192;
        transw_body(Wq, wqkvT, 4096, (idx & 63) * 64, (idx >> 6) * 64, t);
    } else if (bx < 8192 + 2048 + 512) {               // Wk: N=1024
        int idx = bx - (8192 + 2048);
        transw_body(Wk, wqkvT + (size_t)4096 * HID, 1024, (idx & 15) * 64, (idx >> 4) * 64, t);
    } else if (bx < 8192 + 2048 + 1024) {              // Wv: N=1024
        int idx = bx - (8192 + 2048 + 512);
        transw_body(Wv, wqkvT + (size_t)5120 * HID, 1024, (idx & 15) * 64, (idx >> 4) * 64, t);
    } else {                                           // Wo: N=2048
        int idx = bx - (8192 + 2048 + 1024);
        transw_body(Wo, woT, 2048, (idx & 31) * 64, (idx >> 5) * 64, t);
    }
}

// ---------------- MFMA GEMM (128x128, m97 structure) — kept for Wo (N=2048: only
// 128 blocks at 256^2 would idle half the CUs) ----------------
template<bool OUT_BF16>
__global__ __launch_bounds__(256) void gemm_bt(const bf16* __restrict__ A, const bf16* __restrict__ Bt,
                                               void* __restrict__ C, int M, int N, int K) {
    __shared__ __align__(16) bf16 As[128 * 64];   // 16 KB
    __shared__ __align__(16) bf16 Bs[128 * 64];   // 16 KB
    const int tid = threadIdx.x;
    const int wave = tid >> 6, lane = tid & 63;
    const int l31 = lane & 31, half = lane >> 5;
    const int tile_n = blockIdx.x * 128, tile_m = blockIdx.y * 128;
    const int wm = (wave & 1) * 64, wn = (wave >> 1) * 64;
    const int sw = l31 & 7;                             // read-side swizzle
    f32x16 acc[2][2] = {};

    for (int k0 = 0; k0 < K; k0 += 64) {
        __syncthreads();
        #pragma unroll
        for (int j = 0; j < 4; ++j) {
            int s = j * 256 + tid;                       // LDS slot 0..1023 (16B each)
            int row = s >> 3, c = s & 7;
            int cs = c ^ (row & 7);                      // fetch permuted chunk
            GLOAD_LDS16(A  + (size_t)(tile_m + row) * K + k0 + (cs << 3), As + (size_t)s * 8);
            GLOAD_LDS16(Bt + (size_t)(tile_n + row) * K + k0 + (cs << 3), Bs + (size_t)s * 8);
        }
        __syncthreads();
        #pragma unroll
        for (int ks = 0; ks < 4; ++ks) {
            int ch = ((ks * 2 + half) ^ sw) << 3;
            bf16x8 a0 = *(const bf16x8*)(As + (size_t)(wm + l31) * 64 + ch);
            bf16x8 a1 = *(const bf16x8*)(As + (size_t)(wm + 32 + l31) * 64 + ch);
            bf16x8 b0 = *(const bf16x8*)(Bs + (size_t)(wn + l31) * 64 + ch);
            bf16x8 b1 = *(const bf16x8*)(Bs + (size_t)(wn + 32 + l31) * 64 + ch);
            acc[0][0] = __builtin_amdgcn_mfma_f32_32x32x16_bf16(a0, b0, acc[0][0], 0, 0, 0);
            acc[0][1] = __builtin_amdgcn_mfma_f32_32x32x16_bf16(a0, b1, acc[0][1], 0, 0, 0);
            acc[1][0] = __builtin_amdgcn_mfma_f32_32x32x16_bf16(a1, b0, acc[1][0], 0, 0, 0);
            acc[1][1] = __builtin_amdgcn_mfma_f32_32x32x16_bf16(a1, b1, acc[1][1], 0, 0, 0);
        }
    }
    #pragma unroll
    for (int mt = 0; mt < 2; ++mt)
        #pragma unroll
        for (int nt = 0; nt < 2; ++nt)
            #pragma unroll
            for (int reg = 0; reg < 16; ++reg) {
                int row = tile_m + wm + mt * 32 + (reg & 3) + ((reg >> 2) * 8) + half * 4;
                int col = tile_n + wn + nt * 32 + l31;
                float v = acc[mt][nt][reg];
                if (OUT_BF16) ((bf16*)C)[(size_t)row * N + col] = (bf16)v;
                else          ((float*)C)[(size_t)row * N + col] = v;
            }
}

// ---------------- 256x256 8-phase MFMA GEMM (m201 template, plain HIP) ----------------
// 8 waves (2M x 4N), per-wave 128x64 output, BK=64, dbuf LDS 128 KiB.
// Half-tiles split by CONSUMPTION: A-half h = bit6 of tile-row, B-half h = bit5,
// so quadrant (mh,nh) of the gray schedule (00,01,11,10) touches exactly A[mh],B[nh].
// XOR-8 chunk swizzle: LDS chunk-slot c holds global chunk c^(wr&7) (pre-swizzled
// global source, linear LDS dest — rule #21). Counted vmcnt(6) at phases 4/8 only.
__device__ __forceinline__ void stageA256(const bf16* __restrict__ A, int tile_m, int K,
                                          int t, int h, bf16* dst, int tid) {
    int k0 = t << 6;
    #pragma unroll
    for (int j = 0; j < 2; ++j) {
        int s = j * 512 + tid;                 // 16B slot 0..1023
        int wr = s >> 3, c = s & 7;
        int cs = c ^ (wr & 7);
        int gr = ((wr >> 6) << 7) | (h << 6) | (wr & 63);   // rows {0-63,128-191} (h=0) / {64-127,192-255}
        GLOAD_LDS16(A + (size_t)(tile_m + gr) * K + k0 + (cs << 3), dst + (size_t)s * 8);
    }
}
__device__ __forceinline__ void stageB256(const bf16* __restrict__ Bt, int tile_n, int K,
                                          int t, int h, bf16* dst, int tid) {
    int k0 = t << 6;
    #pragma unroll
    for (int j = 0; j < 2; ++j) {
        int s = j * 512 + tid;
        int wr = s >> 3, c = s & 7;
        int cs = c ^ (wr & 7);
        int gr = ((wr >> 5) << 6) | (h << 5) | (wr & 31);   // rows {0-31,64-95,...} (h=0)
        GLOAD_LDS16(Bt + (size_t)(tile_n + gr) * K + k0 + (cs << 3), dst + (size_t)s * 8);
    }
}

__global__ __launch_bounds__(512, 2) void gemm256(const bf16* __restrict__ A, const bf16* __restrict__ Bt,
                                                  bf16* __restrict__ C, int M, int N, int K) {
    __shared__ __align__(16) bf16 As[2][2][128 * 64];   // [slot][half]  64 KiB
    __shared__ __align__(16) bf16 Bs[2][2][128 * 64];   //               64 KiB
    const int tid = threadIdx.x;
    const int wave = tid >> 6, lane = tid & 63;
    const int l15 = lane & 15, quad = lane >> 4;
    const int wrow = wave >> 2, wcol = wave & 3;        // 2M x 4N wave grid
    const int tile_n = blockIdx.x * 256, tile_m = blockIdx.y * 256;

    f32x4 acc[8][4] = {};
    bf16x8 aF[4][2], bF[2][2];

#define LOAD_AF(sl, mh) { \
    const bf16* _ba = &As[sl][mh][0]; \
    _Pragma("unroll") for (int mf2 = 0; mf2 < 4; ++mf2) \
    _Pragma("unroll") for (int ks = 0; ks < 2; ++ks) { \
        int wr = wrow * 64 + mf2 * 16 + l15; \
        int pc = (ks * 4 + quad) ^ (l15 & 7); \
        aF[mf2][ks] = *(const bf16x8*)(_ba + wr * 64 + pc * 8); \
    } }
#define LOAD_BF(sl, nh) { \
    const bf16* _bb = &Bs[sl][nh][0]; \
    _Pragma("unroll") for (int nf2 = 0; nf2 < 2; ++nf2) \
    _Pragma("unroll") for (int ks = 0; ks < 2; ++ks) { \
        int wr = wcol * 32 + nf2 * 16 + l15; \
        int pc = (ks * 4 + quad) ^ (l15 & 7); \
        bF[nf2][ks] = *(const bf16x8*)(_bb + wr * 64 + pc * 8); \
    } }
#define MIDBAR() { __builtin_amdgcn_s_barrier(); \
    asm volatile("s_waitcnt lgkmcnt(0)" ::: "memory"); \
    __builtin_amdgcn_sched_barrier(0); }
#define MFMA16(mh, nh) { \
    __builtin_amdgcn_s_setprio(1); \
    _Pragma("unroll") for (int mf2 = 0; mf2 < 4; ++mf2) \
    _Pragma("unroll") for (int nf2 = 0; nf2 < 2; ++nf2) \
    _Pragma("unroll") for (int ks = 0; ks < 2; ++ks) \
        acc[(mh)*4+mf2][(nh)*2+nf2] = __builtin_amdgcn_mfma_f32_16x16x32_bf16( \
            aF[mf2][ks], bF[nf2][ks], acc[(mh)*4+mf2][(nh)*2+nf2], 0, 0, 0); \
    __builtin_amdgcn_s_setprio(0); }
#define ENDBAR() __builtin_amdgcn_s_barrier();
#define VMCNT6() asm volatile("s_waitcnt vmcnt(6)" ::: "memory");
#define VMCNT0() asm volatile("s_waitcnt vmcnt(0)" ::: "memory");

    const int NITER = K >> 7;   // 2 K-tiles per iteration; requires K%128==0, NITER>=2

    // prologue: tile0 -> slot0 (A0,B0,B1,A1); tile1 -> slot1 (A0,B1,A1; B0 at ph1)
    stageA256(A,  tile_m, K, 0, 0, &As[0][0][0], tid);
    stageB256(Bt, tile_n, K, 0, 0, &Bs[0][0][0], tid);
    stageB256(Bt, tile_n, K, 0, 1, &Bs[0][1][0], tid);
    stageA256(A,  tile_m, K, 0, 1, &As[0][1][0], tid);
    stageA256(A,  tile_m, K, 1, 0, &As[1][0][0], tid);
    stageB256(Bt, tile_n, K, 1, 1, &Bs[1][1][0], tid);
    stageA256(A,  tile_m, K, 1, 1, &As[1][1][0], tid);
    VMCNT6();                       // all of tile0 landed (3 HTs of tile1 may fly)
    __builtin_amdgcn_s_barrier();

    for (int it = 0; it < NITER - 1; ++it) {
        const int T = 2 * it;       // even tile -> slot0, odd -> slot1
        // ph1: q(0,0) slot0; stage B0(T+1)->slot1
        LOAD_AF(0, 0); LOAD_BF(0, 0);
        stageB256(Bt, tile_n, K, T + 1, 0, &Bs[1][0][0], tid);
        MIDBAR(); MFMA16(0, 0); ENDBAR();
        // ph2: q(0,1) slot0 (A reused); stage A0(T+2)->slot0 (A0 free after ph1)
        LOAD_BF(0, 1);
        stageA256(A, tile_m, K, T + 2, 0, &As[0][0][0], tid);
        MIDBAR(); MFMA16(0, 1); ENDBAR();
        // ph3: q(1,1) slot0 (B reused); stage B1(T+2)->slot0
        LOAD_AF(0, 1);
        stageB256(Bt, tile_n, K, T + 2, 1, &Bs[0][1][0], tid);
        MIDBAR(); MFMA16(1, 1); ENDBAR();
        // ph4: q(1,0) slot0 (B0 re-read); stage A1(T+2)->slot0; vmcnt(6)
        LOAD_BF(0, 0);
        stageA256(A, tile_m, K, T + 2, 1, &As[0][1][0], tid);
        MIDBAR(); MFMA16(1, 0); VMCNT6(); ENDBAR();   // tile T+1 fully landed
        // ph5: q(0,0) slot1; stage B0(T+2)->slot0 (B0 free after ph4)
        LOAD_AF(1, 0); LOAD_BF(1, 0);
        stageB256(Bt, tile_n, K, T + 2, 0, &Bs[0][0][0], tid);
        MIDBAR(); MFMA16(0, 0); ENDBAR();
        // ph6: q(0,1) slot1; stage A0(T+3)->slot1
        LOAD_BF(1, 1);
        stageA256(A, tile_m, K, T + 3, 0, &As[1][0][0], tid);
        MIDBAR(); MFMA16(0, 1); ENDBAR();
        // ph7: q(1,1) slot1; stage B1(T+3)->slot1
        LOAD_AF(1, 1);
        stageB256(Bt, tile_n, K, T + 3, 1, &Bs[1][1][0], tid);
        MIDBAR(); MFMA16(1, 1); ENDBAR();
        // ph8: q(1,0) slot1; stage A1(T+3)->slot1; vmcnt(6)
        LOAD_BF(1, 0);
        stageA256(A, tile_m, K, T + 3, 1, &As[1][1][0], tid);
        MIDBAR(); MFMA16(1, 0); VMCNT6(); ENDBAR();   // tile T+2 fully landed
    }
    // last iteration (T = 2*NITER-2): only B0(T+1) still to stage; drain at ph4
    {
        LOAD_AF(0, 0); LOAD_BF(0, 0);
        stageB256(Bt, tile_n, K, 2 * NITER - 1, 0, &Bs[1][0][0], tid);
        MIDBAR(); MFMA16(0, 0); ENDBAR();
        LOAD_BF(0, 1); MIDBAR(); MFMA16(0, 1); ENDBAR();
        LOAD_AF(0, 1); MIDBAR(); MFMA16(1, 1); ENDBAR();
        LOAD_BF(0, 0); MIDBAR(); MFMA16(1, 0); VMCNT0(); ENDBAR();
        LOAD_AF(1, 0); LOAD_BF(1, 0); MIDBAR(); MFMA16(0, 0); ENDBAR();
        LOAD_BF(1, 1); MIDBAR(); MFMA16(0, 1); ENDBAR();
        LOAD_AF(1, 1); MIDBAR(); MFMA16(1, 1); ENDBAR();
        LOAD_BF(1, 0); MIDBAR(); MFMA16(1, 0); ENDBAR();
    }

    // epilogue: 16x16x32 C/D layout: col = lane&15, row = (lane>>4)*4 + reg (m89/m91)
    #pragma unroll
    for (int mf = 0; mf < 8; ++mf)
        #pragma unroll
        for (int nf = 0; nf < 4; ++nf)
            #pragma unroll
            for (int r = 0; r < 4; ++r) {
                int row = tile_m + wrow * 128 + mf * 16 + quad * 4 + r;
                int col = tile_n + wcol * 64 + nf * 16 + l15;
                C[(size_t)row * N + col] = (bf16)acc[mf][nf][r];
            }
#undef LOAD_AF
#undef LOAD_BF
#undef MIDBAR
#undef MFMA16
#undef ENDBAR
#undef VMCNT6
#undef VMCNT0
}

// ---------------- fused post: per-head RMSNorm+RoPE (Q,K) + V transpose ----------------
__global__ __launch_bounds__(256) void post_kernel(const bf16* __restrict__ qkv,
                                                   const float* __restrict__ qnw, const float* __restrict__ knw,
                                                   const int* __restrict__ positions,
                                                   bf16* __restrict__ Qh, bf16* __restrict__ Kh,
                                                   bf16* __restrict__ VT) {
    int bx = blockIdx.x;
    if (bx < 4096) {
        int tk = bx;                      // token 0..4095
        int b = tk >> 11, s = tk & 2047;
        int wave = threadIdx.x >> 6, lane = threadIdx.x & 63;
        int e0 = lane * 2, e1 = e0 + 1;
        float pos = (float)positions[tk];
        const float L = 1.4533435415278355f;    // log2(theta)/16
        float a0 = pos * exp2f(-(float)(e0 & 15) * L);
        float a1 = pos * exp2f(-(float)(e1 & 15) * L);
        float cv0 = cosf(a0), sv0 = sinf(a0);
        float cv1 = cosf(a1), sv1 = sinf(a1);
        float qw0 = 1.0f + qnw[e0], qw1 = 1.0f + qnw[e1];
        float kw0 = 1.0f + knw[e0], kw1 = 1.0f + knw[e1];

        #pragma unroll
        for (int i = 0; i < 6; ++i) {
            bool isq = (i < 4);
            int h = wave + (isq ? i : (i - 4)) * 4;
            const bf16* base = qkv + (size_t)tk * NQKV + (isq ? h * 256 : 4096 + h * HD);
            bf16x2 v = *(const bf16x2*)(base + e0);
            float f0 = (float)v[0], f1 = (float)v[1];
            float ssq = f0 * f0 + f1 * f1;
            #pragma unroll
            for (int off = 32; off; off >>= 1) ssq += __shfl_xor(ssq, off);
            float rn = rsqrtf(ssq * (1.0f / 128.0f) + 1e-6f);
            float w0 = isq ? qw0 : kw0, w1 = isq ? qw1 : kw1;
            float x0 = f0 * rn * w0, x1 = f1 * rn * w1;
            float p0 = __shfl_xor(x0, 8), p1 = __shfl_xor(x1, 8);
            float r0 = x0, r1 = x1;
            if (lane < 8)       { r0 = x0 * cv0 - p0 * sv0; r1 = x1 * cv1 - p1 * sv1; }
            else if (lane < 16) { r0 = p0 * sv0 + x0 * cv0; r1 = p1 * sv1 + x1 * cv1; }
            bf16x2 o; o[0] = (bf16)r0; o[1] = (bf16)r1;
            bf16* dst = isq ? (Qh + ((size_t)(b * NH + h) * SEQ + s) * HD)
                            : (Kh + ((size_t)(b * NKV + h) * SEQ + s) * HD);
            *(bf16x2*)(dst + e0) = o;
        }
    } else {
        int idx = bx - 4096;              // vtrans: 512 blocks
        int bh = idx >> 5, st = idx & 31;
        int b = bh >> 3, h = bh & 7;
        __shared__ float tile[64][129];
        int t = threadIdx.x;
        const bf16* src = qkv + ((size_t)(b * SEQ) + st * 64) * NQKV + 5120 + h * HD;
        #pragma unroll
        for (int i = 0; i < 32; ++i) {
            int ii = i * 256 + t;
            int tok = ii >> 7, d = ii & 127;
            tile[tok][d] = (float)src[(size_t)tok * NQKV + d];
        }
        __syncthreads();
        bf16* dst = VT + (size_t)(b * NKV + h) * HD * SEQ + st * 64;
        #pragma unroll
        for (int i = 0; i < 32; ++i) {
            int ii = i * 256 + t;
            int d = ii >> 6, sx = ii & 63;
            dst[(size_t)d * SEQ + sx] = (bf16)tile[sx][d];
        }
    }
}

// ---------------- flash attention, Br=128, Bc=64, 8 waves x 16 q-rows ----------------
__global__ __launch_bounds__(512, 4) void attn_kernel(const bf16* __restrict__ Qh, const bf16* __restrict__ Kh,
                                                      const bf16* __restrict__ VT, const bf16* __restrict__ qkv,
                                                      const int* __restrict__ amask, bf16* __restrict__ attnb) {
    const int bx = blockIdx.x;              // 512 blocks
    const int hb = (bx >> 4) & 31;          // b*16+head
    const int head = hb & 15, b = hb >> 4;
    int q0 = ((bx & 15) + hb) & 15;
    const int qt = (bx & 256) ? (15 - q0) : q0;   // pair sums constant work
    const int kvh = head >> 1;
    __shared__ __align__(16) bf16 Ks[64 * 128];     // [row][chunk ^ (row&15)]
    __shared__ __align__(16) bf16 Vs[128 * 64];     // [d][chunk ^ (d&7)]
    __shared__ __align__(16) bf16 Ps[8 * 16 * 64];  // per-wave, col ^ ((row>>2)*16)
    const int tid = threadIdx.x, wave = tid >> 6, lane = tid & 63;
    const int quad = lane >> 4, cl = lane & 15;

    const bf16* qsrc = Qh + ((size_t)(b * NH + head) * SEQ + qt * 128) * HD;
    bf16x8 aq[4];
    #pragma unroll
    for (int kc = 0; kc < 4; ++kc)
        aq[kc] = *(const bf16x8*)(qsrc + (size_t)(wave * 16 + cl) * HD + kc * 32 + quad * 8);

    float lstate[4] = {0.0f, 0.0f, 0.0f, 0.0f};
    f32x4 oacc[8] = {};
    const int qrow_glob = qt * 128 + wave * 16 + quad * 4;  // + r
    const float scale = 0.08838834764831845f * 1.4426950408889634f;
    const float M = 20.0f;
    const int kmax = 2 * qt + 1;

    for (int kt = 0; kt <= kmax; ++kt) {
        __syncthreads();
        const bf16* ksrc = Kh + ((size_t)(b * NKV + kvh) * SEQ + kt * 64) * HD;
        const bf16* vsrc = VT + (size_t)(b * NKV + kvh) * HD * SEQ + kt * 64;
        #pragma unroll
        for (int j = 0; j < 2; ++j) {
            int s = j * 512 + tid;                    // 16B-chunk slot 0..1023
            int rK = s >> 4, cK = s & 15;
            GLOAD_LDS16(ksrc + (size_t)rK * HD + ((cK ^ (rK & 15)) << 3), Ks + (size_t)s * 8);
            int dV = s >> 3, cV = s & 7;
            GLOAD_LDS16(vsrc + (size_t)dV * SEQ + ((cV ^ (dV & 7)) << 3), Vs + (size_t)s * 8);
        }
        __syncthreads();

        f32x4 sc[4] = {};
        #pragma unroll
        for (int nt = 0; nt < 4; ++nt)
            #pragma unroll
            for (int kc = 0; kc < 4; ++kc) {
                bf16x8 bk = *(const bf16x8*)(Ks + (size_t)(nt * 16 + cl) * 128 + (((kc * 4 + quad) ^ cl) << 3));
                sc[nt] = __builtin_amdgcn_mfma_f32_16x16x32_bf16(aq[kc], bk, sc[nt], 0, 0, 0);
            }

        #pragma unroll
        for (int nt = 0; nt < 4; ++nt) {
            int kcol = kt * 64 + nt * 16 + cl;
            bool cok = (amask[b * SEQ + kcol] != 0);
            #pragma unroll
            for (int r = 0; r < 4; ++r) {
                bool ok = cok && (kcol <= qrow_glob + r);
                float p = ok ? exp2f(sc[nt][r] * scale - M) : 0.0f;
                lstate[r] += p;
                Ps[wave * 1024 + (quad * 4 + r) * 64 + ((nt * 16 + cl) ^ (quad << 4))] = (bf16)p;
            }
        }

        bf16x8 ap[2];
        #pragma unroll
        for (int c = 0; c < 2; ++c)
            ap[c] = *(const bf16x8*)(Ps + wave * 1024 + cl * 64 + ((c * 32 + quad * 8) ^ ((cl >> 2) << 4)));
        #pragma unroll
        for (int n2 = 0; n2 < 8; ++n2)
            #pragma unroll
            for (int c = 0; c < 2; ++c) {
                bf16x8 bv = *(const bf16x8*)(Vs + (size_t)(n2 * 16 + cl) * 64 + (((c * 4 + quad) ^ (cl & 7)) << 3));
                oacc[n2] = __builtin_amdgcn_mfma_f32_16x16x32_bf16(ap[c], bv, oacc[n2], 0, 0, 0);
            }
    }

    #pragma unroll
    for (int r = 0; r < 4; ++r) {
        #pragma unroll
        for (int off = 8; off; off >>= 1) lstate[r] += __shfl_xor(lstate[r], off);
        int srow = qt * 128 + wave * 16 + quad * 4 + r;
        float linv = 1.0f / lstate[r];
        #pragma unroll
        for (int n2 = 0; n2 < 8; ++n2) {
            int d = n2 * 16 + cl;
            float g = (float)qkv[(size_t)(b * SEQ + srow) * NQKV + head * 256 + 128 + d];
            float sig = 1.0f / (1.0f + __expf(-g));
            float v = oacc[n2][r] * linv * sig;
            attnb[(size_t)(b * SEQ + srow) * HID + head * HD + d] = (bf16)v;
        }
    }
}

// ---------------- launch ----------------
extern "C" void kernel_launch(void* const* d_in, const int* in_sizes, int n_in,
                              void* d_out, int out_size, void* d_ws, size_t ws_size,
                              hipStream_t stream) {
    const float* x        = (const float*)d_in[0];
    const int*   amask    = (const int*)d_in[1];
    const int*   positions= (const int*)d_in[2];
    const float* Wq       = (const float*)d_in[3];
    const float* Wk       = (const float*)d_in[4];
    const float* Wv       = (const float*)d_in[5];
    const float* Wo       = (const float*)d_in[6];
    const float* qnw      = (const float*)d_in[7];
    const float* knw      = (const float*)d_in[8];
    float* out = (float*)d_out;
    char* ws = (char*)d_ws;

    bf16* xb    = (bf16*)(ws);                         // 16,777,216 B
    bf16* wqkvT = (bf16*)(ws + 16777216);              // 25,165,824 B
    bf16* woT   = (bf16*)(ws + 41943040);              //  8,388,608 B
    bf16* qkv   = (bf16*)(ws + 50331648);              // 50,331,648 B
    bf16* Qh    = (bf16*)(ws + 100663296);             // 16,777,216 B
    bf16* Kh    = (bf16*)(ws + 117440512);             //  8,388,608 B
    bf16* VT    = (bf16*)(ws + 125829120);             //  8,388,608 B
    bf16* attnb = (bf16*)(ws + 134217728);             // 16,777,216 B -> 150,994,944 total

    prep_kernel<<<12288, 256, 0, stream>>>(x, xb, Wq, Wk, Wv, Wo, wqkvT, woT);
    gemm256<<<dim3(NQKV / 256, MTOT / 256), 512, 0, stream>>>(xb, wqkvT, qkv, MTOT, NQKV, HID);
    post_kernel<<<4608, 256, 0, stream>>>(qkv, qnw, knw, positions, Qh, Kh, VT);
    attn_kernel<<<512, 512, 0, stream>>>(Qh, Kh, VT, qkv, amask, attnb);
    gemm_bt<false><<<dim3(16, 32), 256, 0, stream>>>(attnb, woT, out, MTOT, HID, HID);

    (void)in_sizes; (void)n_in; (void)out_size; (void)ws_size;
}

// Round 3
// 407.732 us; speedup vs baseline: 1.0131x; 1.0131x over previous
//
#include <hip/hip_runtime.h>
#include <cstdint>

// ---- types ----
typedef __bf16  bf16;
typedef __bf16  bf16x8 __attribute__((ext_vector_type(8)));
typedef __bf16  bf16x4 __attribute__((ext_vector_type(4)));
typedef __bf16  bf16x2 __attribute__((ext_vector_type(2)));
typedef float   f32x4  __attribute__((ext_vector_type(4)));
typedef float   f32x16 __attribute__((ext_vector_type(16)));

#define GLOAD_LDS16(g, l) __builtin_amdgcn_global_load_lds( \
    (const __attribute__((address_space(1))) void*)(g),     \
    (__attribute__((address_space(3))) void*)(l), 16, 0, 0)

// dims
#define SEQ   2048
#define HID   2048
#define NH    16
#define NKV   8
#define HD    128
#define NQKV  6144   // 4096 q_all + 1024 k + 1024 v
#define MTOT  4096   // B*SEQ

// ---------------- fused prep: convx + all weight transposes ----------------
__device__ __forceinline__ void transw_body(const float* __restrict__ W, bf16* __restrict__ WT,
                                            int N, int n0, int k0, int t) {
    __shared__ float tile[64][65];
    int tn = t & 63, t4 = t >> 6;
    #pragma unroll
    for (int i = 0; i < 16; ++i) {
        int kk = i * 4 + t4;
        tile[kk][tn] = W[(size_t)(k0 + kk) * N + n0 + tn];
    }
    __syncthreads();
    #pragma unroll
    for (int i = 0; i < 16; ++i) {
        int nn = i * 4 + t4;
        WT[(size_t)(n0 + nn) * HID + k0 + tn] = (bf16)tile[tn][nn];
    }
}

__global__ __launch_bounds__(256) void prep_kernel(const float* __restrict__ x, bf16* __restrict__ xb,
                                                   const float* __restrict__ Wq, const float* __restrict__ Wk,
                                                   const float* __restrict__ Wv, const float* __restrict__ Wo,
                                                   bf16* __restrict__ wqkvT, bf16* __restrict__ woT) {
    int bx = blockIdx.x, t = threadIdx.x;
    if (bx < 8192) {                                   // convx: 4 f32->bf16 per thread
        int i = bx * 256 + t;
        f32x4 v = ((const f32x4*)x)[i];
        bf16x4 o;
        o[0] = (bf16)v[0]; o[1] = (bf16)v[1]; o[2] = (bf16)v[2]; o[3] = (bf16)v[3];
        ((bf16x4*)xb)[i] = o;
    } else if (bx < 8192 + 2048) {                     // Wq: N=4096
        int idx = bx - 8192;
        transw_body(Wq, wqkvT, 4096, (idx & 63) * 64, (idx >> 6) * 64, t);
    } else if (bx < 8192 + 2048 + 512) {               // Wk: N=1024
        int idx = bx - (8192 + 2048);
        transw_body(Wk, wqkvT + (size_t)4096 * HID, 1024, (idx & 15) * 64, (idx >> 4) * 64, t);
    } else if (bx < 8192 + 2048 + 1024) {              // Wv: N=1024
        int idx = bx - (8192 + 2048 + 512);
        transw_body(Wv, wqkvT + (size_t)5120 * HID, 1024, (idx & 15) * 64, (idx >> 4) * 64, t);
    } else {                                           // Wo: N=2048
        int idx = bx - (8192 + 2048 + 1024);
        transw_body(Wo, woT, 2048, (idx & 31) * 64, (idx >> 5) * 64, t);
    }
}

// ---------------- MFMA GEMM (128x128, m97 structure) — kept for Wo ----------------
template<bool OUT_BF16>
__global__ __launch_bounds__(256) void gemm_bt(const bf16* __restrict__ A, const bf16* __restrict__ Bt,
                                               void* __restrict__ C, int M, int N, int K) {
    __shared__ __align__(16) bf16 As[128 * 64];   // 16 KB
    __shared__ __align__(16) bf16 Bs[128 * 64];   // 16 KB
    const int tid = threadIdx.x;
    const int wave = tid >> 6, lane = tid & 63;
    const int l31 = lane & 31, half = lane >> 5;
    const int tile_n = blockIdx.x * 128, tile_m = blockIdx.y * 128;
    const int wm = (wave & 1) * 64, wn = (wave >> 1) * 64;
    const int sw = l31 & 7;                             // read-side swizzle
    f32x16 acc[2][2] = {};

    for (int k0 = 0; k0 < K; k0 += 64) {
        __syncthreads();
        #pragma unroll
        for (int j = 0; j < 4; ++j) {
            int s = j * 256 + tid;                       // LDS slot 0..1023 (16B each)
            int row = s >> 3, c = s & 7;
            int cs = c ^ (row & 7);                      // fetch permuted chunk
            GLOAD_LDS16(A  + (size_t)(tile_m + row) * K + k0 + (cs << 3), As + (size_t)s * 8);
            GLOAD_LDS16(Bt + (size_t)(tile_n + row) * K + k0 + (cs << 3), Bs + (size_t)s * 8);
        }
        __syncthreads();
        #pragma unroll
        for (int ks = 0; ks < 4; ++ks) {
            int ch = ((ks * 2 + half) ^ sw) << 3;
            bf16x8 a0 = *(const bf16x8*)(As + (size_t)(wm + l31) * 64 + ch);
            bf16x8 a1 = *(const bf16x8*)(As + (size_t)(wm + 32 + l31) * 64 + ch);
            bf16x8 b0 = *(const bf16x8*)(Bs + (size_t)(wn + l31) * 64 + ch);
            bf16x8 b1 = *(const bf16x8*)(Bs + (size_t)(wn + 32 + l31) * 64 + ch);
            acc[0][0] = __builtin_amdgcn_mfma_f32_32x32x16_bf16(a0, b0, acc[0][0], 0, 0, 0);
            acc[0][1] = __builtin_amdgcn_mfma_f32_32x32x16_bf16(a0, b1, acc[0][1], 0, 0, 0);
            acc[1][0] = __builtin_amdgcn_mfma_f32_32x32x16_bf16(a1, b0, acc[1][0], 0, 0, 0);
            acc[1][1] = __builtin_amdgcn_mfma_f32_32x32x16_bf16(a1, b1, acc[1][1], 0, 0, 0);
        }
    }
    #pragma unroll
    for (int mt = 0; mt < 2; ++mt)
        #pragma unroll
        for (int nt = 0; nt < 2; ++nt)
            #pragma unroll
            for (int reg = 0; reg < 16; ++reg) {
                int row = tile_m + wm + mt * 32 + (reg & 3) + ((reg >> 2) * 8) + half * 4;
                int col = tile_n + wn + nt * 32 + l31;
                float v = acc[mt][nt][reg];
                if (OUT_BF16) ((bf16*)C)[(size_t)row * N + col] = (bf16)v;
                else          ((float*)C)[(size_t)row * N + col] = v;
            }
}

// ---------------- 256x256 8-phase MFMA GEMM ----------------
// Round-2 post-mortem: the bare one-barrier phases raced — the machine scheduler
// can sink register-only MFMAs (and their ds_reads' lgkm waits) past a bare
// s_barrier (rule #18 precedent), so a wave could cross barrier p with phase-p
// LDS reads pending while another wave, already released, overwrites that buffer
// via global_load_lds (vmcnt and lgkm queues are UNORDERED in HW). Fix: bracket
// each barrier with sched_barrier(0) — a compile-time-only fence pinning phase
// contents to their phase; intra-phase scheduling (stage-first, progressive
// lgkmcnt into the MFMA cluster) stays free. No runtime drain.
__device__ __forceinline__ void stageA256(const bf16* __restrict__ A, int tile_m, int K,
                                          int t, int h, bf16* dst, int tid) {
    int k0 = t << 6;
    #pragma unroll
    for (int j = 0; j < 2; ++j) {
        int s = j * 512 + tid;                 // 16B slot 0..1023
        int wr = s >> 3, c = s & 7;
        int cs = c ^ (wr & 7);
        int gr = ((wr >> 6) << 7) | (h << 6) | (wr & 63);   // rows {0-63,128-191} (h=0) / complement
        GLOAD_LDS16(A + (size_t)(tile_m + gr) * K + k0 + (cs << 3), dst + (size_t)s * 8);
    }
}
__device__ __forceinline__ void stageB256(const bf16* __restrict__ Bt, int tile_n, int K,
                                          int t, int h, bf16* dst, int tid) {
    int k0 = t << 6;
    #pragma unroll
    for (int j = 0; j < 2; ++j) {
        int s = j * 512 + tid;
        int wr = s >> 3, c = s & 7;
        int cs = c ^ (wr & 7);
        int gr = ((wr >> 5) << 6) | (h << 5) | (wr & 31);   // rows {0-31,64-95,...} (h=0)
        GLOAD_LDS16(Bt + (size_t)(tile_n + gr) * K + k0 + (cs << 3), dst + (size_t)s * 8);
    }
}

__global__ __launch_bounds__(512, 2) void gemm256(const bf16* __restrict__ A, const bf16* __restrict__ Bt,
                                                  bf16* __restrict__ C, int M, int N, int K) {
    __shared__ __align__(16) bf16 As[2][2][128 * 64];   // [slot][half]  64 KiB
    __shared__ __align__(16) bf16 Bs[2][2][128 * 64];   //               64 KiB
    const int tid = threadIdx.x;
    const int wave = tid >> 6, lane = tid & 63;
    const int l15 = lane & 15, quad = lane >> 4;
    const int wrow = wave >> 2, wcol = wave & 3;        // 2M x 4N wave grid
    const int tile_n = blockIdx.x * 256, tile_m = blockIdx.y * 256;

    f32x4 acc[8][4] = {};
    bf16x8 aF[4][2], bF[2][2];

#define LOAD_AF(sl, mh) { \
    const bf16* _ba = &As[sl][mh][0]; \
    _Pragma("unroll") for (int mf2 = 0; mf2 < 4; ++mf2) \
    _Pragma("unroll") for (int ks = 0; ks < 2; ++ks) { \
        int wr = wrow * 64 + mf2 * 16 + l15; \
        int pc = (ks * 4 + quad) ^ (l15 & 7); \
        aF[mf2][ks] = *(const bf16x8*)(_ba + wr * 64 + pc * 8); \
    } }
#define LOAD_BF(sl, nh) { \
    const bf16* _bb = &Bs[sl][nh][0]; \
    _Pragma("unroll") for (int nf2 = 0; nf2 < 2; ++nf2) \
    _Pragma("unroll") for (int ks = 0; ks < 2; ++ks) { \
        int wr = wcol * 32 + nf2 * 16 + l15; \
        int pc = (ks * 4 + quad) ^ (l15 & 7); \
        bF[nf2][ks] = *(const bf16x8*)(_bb + wr * 64 + pc * 8); \
    } }
#define MFMA16(mh, nh) { \
    __builtin_amdgcn_s_setprio(1); \
    _Pragma("unroll") for (int mf2 = 0; mf2 < 4; ++mf2) \
    _Pragma("unroll") for (int nf2 = 0; nf2 < 2; ++nf2) \
    _Pragma("unroll") for (int ks = 0; ks < 2; ++ks) \
        acc[(mh)*4+mf2][(nh)*2+nf2] = __builtin_amdgcn_mfma_f32_16x16x32_bf16( \
            aF[mf2][ks], bF[nf2][ks], acc[(mh)*4+mf2][(nh)*2+nf2], 0, 0, 0); \
    __builtin_amdgcn_s_setprio(0); }
#define PHASE_BAR() { __builtin_amdgcn_sched_barrier(0); \
    __builtin_amdgcn_s_barrier(); \
    __builtin_amdgcn_sched_barrier(0); }
#define VMCNT6() asm volatile("s_waitcnt vmcnt(6)" ::: "memory");
#define VMCNT0() asm volatile("s_waitcnt vmcnt(0)" ::: "memory");

    const int NITER = K >> 7;   // 2 K-tiles per iteration; requires K%128==0, NITER>=2

    // prologue: tile0 -> slot0 (A0,B0,B1,A1); tile1 -> slot1 (A0,B1,A1; B0 at ph1)
    stageA256(A,  tile_m, K, 0, 0, &As[0][0][0], tid);
    stageB256(Bt, tile_n, K, 0, 0, &Bs[0][0][0], tid);
    stageB256(Bt, tile_n, K, 0, 1, &Bs[0][1][0], tid);
    stageA256(A,  tile_m, K, 0, 1, &As[0][1][0], tid);
    stageA256(A,  tile_m, K, 1, 0, &As[1][0][0], tid);
    stageB256(Bt, tile_n, K, 1, 1, &Bs[1][1][0], tid);
    stageA256(A,  tile_m, K, 1, 1, &As[1][1][0], tid);
    VMCNT6();                       // all of tile0 landed (3 HTs of tile1 may fly)
    PHASE_BAR();

    for (int it = 0; it < NITER - 1; ++it) {
        const int T = 2 * it;       // even tile -> slot0, odd -> slot1
        // ph1: q(0,0) slot0; stage B0(T+1)->slot1
        stageB256(Bt, tile_n, K, T + 1, 0, &Bs[1][0][0], tid);
        LOAD_AF(0, 0); LOAD_BF(0, 0);
        MFMA16(0, 0); PHASE_BAR();
        // ph2: q(0,1) slot0 (A reused); stage A0(T+2)->slot0 (A0 free after ph1)
        stageA256(A, tile_m, K, T + 2, 0, &As[0][0][0], tid);
        LOAD_BF(0, 1);
        MFMA16(0, 1); PHASE_BAR();
        // ph3: q(1,1) slot0 (B reused); stage B1(T+2)->slot0
        stageB256(Bt, tile_n, K, T + 2, 1, &Bs[0][1][0], tid);
        LOAD_AF(0, 1);
        MFMA16(1, 1); PHASE_BAR();
        // ph4: q(1,0) slot0 (B0 re-read); stage A1(T+2)->slot0; vmcnt(6)
        stageA256(A, tile_m, K, T + 2, 1, &As[0][1][0], tid);
        LOAD_BF(0, 0);
        MFMA16(1, 0); VMCNT6(); PHASE_BAR();          // tile T+1 fully landed
        // ph5: q(0,0) slot1; stage B0(T+2)->slot0 (B0 free after ph4)
        stageB256(Bt, tile_n, K, T + 2, 0, &Bs[0][0][0], tid);
        LOAD_AF(1, 0); LOAD_BF(1, 0);
        MFMA16(0, 0); PHASE_BAR();
        // ph6: q(0,1) slot1; stage A0(T+3)->slot1
        stageA256(A, tile_m, K, T + 3, 0, &As[1][0][0], tid);
        LOAD_BF(1, 1);
        MFMA16(0, 1); PHASE_BAR();
        // ph7: q(1,1) slot1; stage B1(T+3)->slot1
        stageB256(Bt, tile_n, K, T + 3, 1, &Bs[1][1][0], tid);
        LOAD_AF(1, 1);
        MFMA16(1, 1); PHASE_BAR();
        // ph8: q(1,0) slot1; stage A1(T+3)->slot1; vmcnt(6)
        stageA256(A, tile_m, K, T + 3, 1, &As[1][1][0], tid);
        LOAD_BF(1, 0);
        MFMA16(1, 0); VMCNT6(); PHASE_BAR();          // tile T+2 fully landed
    }
    // last iteration (T = 2*NITER-2): only B0(T+1) still to stage; drain at ph4
    {
        stageB256(Bt, tile_n, K, 2 * NITER - 1, 0, &Bs[1][0][0], tid);
        LOAD_AF(0, 0); LOAD_BF(0, 0);
        MFMA16(0, 0); PHASE_BAR();
        LOAD_BF(0, 1); MFMA16(0, 1); PHASE_BAR();
        LOAD_AF(0, 1); MFMA16(1, 1); PHASE_BAR();
        LOAD_BF(0, 0); MFMA16(1, 0); VMCNT0(); PHASE_BAR();
        LOAD_AF(1, 0); LOAD_BF(1, 0); MFMA16(0, 0); PHASE_BAR();
        LOAD_BF(1, 1); MFMA16(0, 1); PHASE_BAR();
        LOAD_AF(1, 1); MFMA16(1, 1); PHASE_BAR();
        LOAD_BF(1, 0); MFMA16(1, 0); PHASE_BAR();
    }

    // epilogue: 16x16x32 C/D layout: col = lane&15, row = (lane>>4)*4 + reg (m89/m91)
    #pragma unroll
    for (int mf = 0; mf < 8; ++mf)
        #pragma unroll
        for (int nf = 0; nf < 4; ++nf)
            #pragma unroll
            for (int r = 0; r < 4; ++r) {
                int row = tile_m + wrow * 128 + mf * 16 + quad * 4 + r;
                int col = tile_n + wcol * 64 + nf * 16 + l15;
                C[(size_t)row * N + col] = (bf16)acc[mf][nf][r];
            }
#undef LOAD_AF
#undef LOAD_BF
#undef MFMA16
#undef PHASE_BAR
#undef VMCNT6
#undef VMCNT0
}

// ---------------- fused post: per-head RMSNorm+RoPE (Q,K) + V transpose ----------------
__global__ __launch_bounds__(256) void post_kernel(const bf16* __restrict__ qkv,
                                                   const float* __restrict__ qnw, const float* __restrict__ knw,
                                                   const int* __restrict__ positions,
                                                   bf16* __restrict__ Qh, bf16* __restrict__ Kh,
                                                   bf16* __restrict__ VT) {
    int bx = blockIdx.x;
    if (bx < 4096) {
        int tk = bx;                      // token 0..4095
        int b = tk >> 11, s = tk & 2047;
        int wave = threadIdx.x >> 6, lane = threadIdx.x & 63;
        int e0 = lane * 2, e1 = e0 + 1;
        float pos = (float)positions[tk];
        const float L = 1.4533435415278355f;    // log2(theta)/16
        float a0 = pos * exp2f(-(float)(e0 & 15) * L);
        float a1 = pos * exp2f(-(float)(e1 & 15) * L);
        float cv0 = cosf(a0), sv0 = sinf(a0);
        float cv1 = cosf(a1), sv1 = sinf(a1);
        float qw0 = 1.0f + qnw[e0], qw1 = 1.0f + qnw[e1];
        float kw0 = 1.0f + knw[e0], kw1 = 1.0f + knw[e1];

        #pragma unroll
        for (int i = 0; i < 6; ++i) {
            bool isq = (i < 4);
            int h = wave + (isq ? i : (i - 4)) * 4;
            const bf16* base = qkv + (size_t)tk * NQKV + (isq ? h * 256 : 4096 + h * HD);
            bf16x2 v = *(const bf16x2*)(base + e0);
            float f0 = (float)v[0], f1 = (float)v[1];
            float ssq = f0 * f0 + f1 * f1;
            #pragma unroll
            for (int off = 32; off; off >>= 1) ssq += __shfl_xor(ssq, off);
            float rn = rsqrtf(ssq * (1.0f / 128.0f) + 1e-6f);
            float w0 = isq ? qw0 : kw0, w1 = isq ? qw1 : kw1;
            float x0 = f0 * rn * w0, x1 = f1 * rn * w1;
            float p0 = __shfl_xor(x0, 8), p1 = __shfl_xor(x1, 8);
            float r0 = x0, r1 = x1;
            if (lane < 8)       { r0 = x0 * cv0 - p0 * sv0; r1 = x1 * cv1 - p1 * sv1; }
            else if (lane < 16) { r0 = p0 * sv0 + x0 * cv0; r1 = p1 * sv1 + x1 * cv1; }
            bf16x2 o; o[0] = (bf16)r0; o[1] = (bf16)r1;
            bf16* dst = isq ? (Qh + ((size_t)(b * NH + h) * SEQ + s) * HD)
                            : (Kh + ((size_t)(b * NKV + h) * SEQ + s) * HD);
            *(bf16x2*)(dst + e0) = o;
        }
    } else {
        int idx = bx - 4096;              // vtrans: 512 blocks
        int bh = idx >> 5, st = idx & 31;
        int b = bh >> 3, h = bh & 7;
        __shared__ float tile[64][129];
        int t = threadIdx.x;
        const bf16* src = qkv + ((size_t)(b * SEQ) + st * 64) * NQKV + 5120 + h * HD;
        #pragma unroll
        for (int i = 0; i < 32; ++i) {
            int ii = i * 256 + t;
            int tok = ii >> 7, d = ii & 127;
            tile[tok][d] = (float)src[(size_t)tok * NQKV + d];
        }
        __syncthreads();
        bf16* dst = VT + (size_t)(b * NKV + h) * HD * SEQ + st * 64;
        #pragma unroll
        for (int i = 0; i < 32; ++i) {
            int ii = i * 256 + t;
            int d = ii >> 6, sx = ii & 63;
            dst[(size_t)d * SEQ + sx] = (bf16)tile[sx][d];
        }
    }
}

// ---------------- flash attention, Br=128, Bc=64, 8 waves x 16 q-rows ----------------
__global__ __launch_bounds__(512, 4) void attn_kernel(const bf16* __restrict__ Qh, const bf16* __restrict__ Kh,
                                                      const bf16* __restrict__ VT, const bf16* __restrict__ qkv,
                                                      const int* __restrict__ amask, bf16* __restrict__ attnb) {
    const int bx = blockIdx.x;              // 512 blocks
    const int hb = (bx >> 4) & 31;          // b*16+head
    const int head = hb & 15, b = hb >> 4;
    int q0 = ((bx & 15) + hb) & 15;
    const int qt = (bx & 256) ? (15 - q0) : q0;   // pair sums constant work
    const int kvh = head >> 1;
    __shared__ __align__(16) bf16 Ks[64 * 128];     // [row][chunk ^ (row&15)]
    __shared__ __align__(16) bf16 Vs[128 * 64];     // [d][chunk ^ (d&7)]
    __shared__ __align__(16) bf16 Ps[8 * 16 * 64];  // per-wave, col ^ ((row>>2)*16)
    const int tid = threadIdx.x, wave = tid >> 6, lane = tid & 63;
    const int quad = lane >> 4, cl = lane & 15;

    const bf16* qsrc = Qh + ((size_t)(b * NH + head) * SEQ + qt * 128) * HD;
    bf16x8 aq[4];
    #pragma unroll
    for (int kc = 0; kc < 4; ++kc)
        aq[kc] = *(const bf16x8*)(qsrc + (size_t)(wave * 16 + cl) * HD + kc * 32 + quad * 8);

    float lstate[4] = {0.0f, 0.0f, 0.0f, 0.0f};
    f32x4 oacc[8] = {};
    const int qrow_glob = qt * 128 + wave * 16 + quad * 4;  // + r
    const float scale = 0.08838834764831845f * 1.4426950408889634f;
    const float M = 20.0f;
    const int kmax = 2 * qt + 1;

    for (int kt = 0; kt <= kmax; ++kt) {
        __syncthreads();
        const bf16* ksrc = Kh + ((size_t)(b * NKV + kvh) * SEQ + kt * 64) * HD;
        const bf16* vsrc = VT + (size_t)(b * NKV + kvh) * HD * SEQ + kt * 64;
        #pragma unroll
        for (int j = 0; j < 2; ++j) {
            int s = j * 512 + tid;                    // 16B-chunk slot 0..1023
            int rK = s >> 4, cK = s & 15;
            GLOAD_LDS16(ksrc + (size_t)rK * HD + ((cK ^ (rK & 15)) << 3), Ks + (size_t)s * 8);
            int dV = s >> 3, cV = s & 7;
            GLOAD_LDS16(vsrc + (size_t)dV * SEQ + ((cV ^ (dV & 7)) << 3), Vs + (size_t)s * 8);
        }
        __syncthreads();

        f32x4 sc[4] = {};
        #pragma unroll
        for (int nt = 0; nt < 4; ++nt)
            #pragma unroll
            for (int kc = 0; kc < 4; ++kc) {
                bf16x8 bk = *(const bf16x8*)(Ks + (size_t)(nt * 16 + cl) * 128 + (((kc * 4 + quad) ^ cl) << 3));
                sc[nt] = __builtin_amdgcn_mfma_f32_16x16x32_bf16(aq[kc], bk, sc[nt], 0, 0, 0);
            }

        #pragma unroll
        for (int nt = 0; nt < 4; ++nt) {
            int kcol = kt * 64 + nt * 16 + cl;
            bool cok = (amask[b * SEQ + kcol] != 0);
            #pragma unroll
            for (int r = 0; r < 4; ++r) {
                bool ok = cok && (kcol <= qrow_glob + r);
                float p = ok ? exp2f(sc[nt][r] * scale - M) : 0.0f;
                lstate[r] += p;
                Ps[wave * 1024 + (quad * 4 + r) * 64 + ((nt * 16 + cl) ^ (quad << 4))] = (bf16)p;
            }
        }

        bf16x8 ap[2];
        #pragma unroll
        for (int c = 0; c < 2; ++c)
            ap[c] = *(const bf16x8*)(Ps + wave * 1024 + cl * 64 + ((c * 32 + quad * 8) ^ ((cl >> 2) << 4)));
        #pragma unroll
        for (int n2 = 0; n2 < 8; ++n2)
            #pragma unroll
            for (int c = 0; c < 2; ++c) {
                bf16x8 bv = *(const bf16x8*)(Vs + (size_t)(n2 * 16 + cl) * 64 + (((c * 4 + quad) ^ (cl & 7)) << 3));
                oacc[n2] = __builtin_amdgcn_mfma_f32_16x16x32_bf16(ap[c], bv, oacc[n2], 0, 0, 0);
            }
    }

    #pragma unroll
    for (int r = 0; r < 4; ++r) {
        #pragma unroll
        for (int off = 8; off; off >>= 1) lstate[r] += __shfl_xor(lstate[r], off);
        int srow = qt * 128 + wave * 16 + quad * 4 + r;
        float linv = 1.0f / lstate[r];
        #pragma unroll
        for (int n2 = 0; n2 < 8; ++n2) {
            int d = n2 * 16 + cl;
            float g = (float)qkv[(size_t)(b * SEQ + srow) * NQKV + head * 256 + 128 + d];
            float sig = 1.0f / (1.0f + __expf(-g));
            float v = oacc[n2][r] * linv * sig;
            attnb[(size_t)(b * SEQ + srow) * HID + head * HD + d] = (bf16)v;
        }
    }
}

// ---------------- launch ----------------
extern "C" void kernel_launch(void* const* d_in, const int* in_sizes, int n_in,
                              void* d_out, int out_size, void* d_ws, size_t ws_size,
                              hipStream_t stream) {
    const float* x        = (const float*)d_in[0];
    const int*   amask    = (const int*)d_in[1];
    const int*   positions= (const int*)d_in[2];
    const float* Wq       = (const float*)d_in[3];
    const float* Wk       = (const float*)d_in[4];
    const float* Wv       = (const float*)d_in[5];
    const float* Wo       = (const float*)d_in[6];
    const float* qnw      = (const float*)d_in[7];
    const float* knw      = (const float*)d_in[8];
    float* out = (float*)d_out;
    char* ws = (char*)d_ws;

    bf16* xb    = (bf16*)(ws);                         // 16,777,216 B
    bf16* wqkvT = (bf16*)(ws + 16777216);              // 25,165,824 B
    bf16* woT   = (bf16*)(ws + 41943040);              //  8,388,608 B
    bf16* qkv   = (bf16*)(ws + 50331648);              // 50,331,648 B
    bf16* Qh    = (bf16*)(ws + 100663296);             // 16,777,216 B
    bf16* Kh    = (bf16*)(ws + 117440512);             //  8,388,608 B
    bf16* VT    = (bf16*)(ws + 125829120);             //  8,388,608 B
    bf16* attnb = (bf16*)(ws + 134217728);             // 16,777,216 B -> 150,994,944 total

    prep_kernel<<<12288, 256, 0, stream>>>(x, xb, Wq, Wk, Wv, Wo, wqkvT, woT);
    gemm256<<<dim3(NQKV / 256, MTOT / 256), 512, 0, stream>>>(xb, wqkvT, qkv, MTOT, NQKV, HID);
    post_kernel<<<4608, 256, 0, stream>>>(qkv, qnw, knw, positions, Qh, Kh, VT);
    attn_kernel<<<512, 512, 0, stream>>>(Qh, Kh, VT, qkv, amask, attnb);
    gemm_bt<false><<<dim3(16, 32), 256, 0, stream>>>(attnb, woT, out, MTOT, HID, HID);

    (void)in_sizes; (void)n_in; (void)out_size; (void)ws_size;
}

// Round 4
// 390.482 us; speedup vs baseline: 1.0579x; 1.0442x over previous
//
#include <hip/hip_runtime.h>
#include <cstdint>

// ---- types ----
typedef __bf16  bf16;
typedef __bf16  bf16x8 __attribute__((ext_vector_type(8)));
typedef __bf16  bf16x4 __attribute__((ext_vector_type(4)));
typedef __bf16  bf16x2 __attribute__((ext_vector_type(2)));
typedef float   f32x4  __attribute__((ext_vector_type(4)));
typedef float   f32x16 __attribute__((ext_vector_type(16)));

#define GLOAD_LDS16(g, l) __builtin_amdgcn_global_load_lds( \
    (const __attribute__((address_space(1))) void*)(g),     \
    (__attribute__((address_space(3))) void*)(l), 16, 0, 0)

// dims
#define SEQ   2048
#define HID   2048
#define NH    16
#define NKV   8
#define HD    128
#define NQKV  6144   // 4096 q_all + 1024 k + 1024 v
#define MTOT  4096   // B*SEQ

// ---------------- fused prep: convx + all weight transposes ----------------
__device__ __forceinline__ void transw_body(const float* __restrict__ W, bf16* __restrict__ WT,
                                            int N, int n0, int k0, int t) {
    __shared__ float tile[64][65];
    int tn = t & 63, t4 = t >> 6;
    #pragma unroll
    for (int i = 0; i < 16; ++i) {
        int kk = i * 4 + t4;
        tile[kk][tn] = W[(size_t)(k0 + kk) * N + n0 + tn];
    }
    __syncthreads();
    #pragma unroll
    for (int i = 0; i < 16; ++i) {
        int nn = i * 4 + t4;
        WT[(size_t)(n0 + nn) * HID + k0 + tn] = (bf16)tile[tn][nn];
    }
}

__global__ __launch_bounds__(256) void prep_kernel(const float* __restrict__ x, bf16* __restrict__ xb,
                                                   const float* __restrict__ Wq, const float* __restrict__ Wk,
                                                   const float* __restrict__ Wv, const float* __restrict__ Wo,
                                                   bf16* __restrict__ wqkvT, bf16* __restrict__ woT) {
    int bx = blockIdx.x, t = threadIdx.x;
    if (bx < 8192) {                                   // convx: 4 f32->bf16 per thread
        int i = bx * 256 + t;
        f32x4 v = ((const f32x4*)x)[i];
        bf16x4 o;
        o[0] = (bf16)v[0]; o[1] = (bf16)v[1]; o[2] = (bf16)v[2]; o[3] = (bf16)v[3];
        ((bf16x4*)xb)[i] = o;
    } else if (bx < 8192 + 2048) {                     // Wq: N=4096
        int idx = bx - 8192;
        transw_body(Wq, wqkvT, 4096, (idx & 63) * 64, (idx >> 6) * 64, t);
    } else if (bx < 8192 + 2048 + 512) {               // Wk: N=1024
        int idx = bx - (8192 + 2048);
        transw_body(Wk, wqkvT + (size_t)4096 * HID, 1024, (idx & 15) * 64, (idx >> 4) * 64, t);
    } else if (bx < 8192 + 2048 + 1024) {              // Wv: N=1024
        int idx = bx - (8192 + 2048 + 512);
        transw_body(Wv, wqkvT + (size_t)5120 * HID, 1024, (idx & 15) * 64, (idx >> 4) * 64, t);
    } else {                                           // Wo: N=2048
        int idx = bx - (8192 + 2048 + 1024);
        transw_body(Wo, woT, 2048, (idx & 31) * 64, (idx >> 5) * 64, t);
    }
}

// ---------------- MFMA GEMM: C[M,N] = A[M,K] * Bt[N,K]^T ----------------
// 128x128 tile, BK=64, 4 waves (64x64 quadrants), 32x32x16 MFMA.
// (256^2 8-phase experiment concluded NULL rounds 1-3: best 131 µs / 31% MfmaUtil
// vs this kernel's 119.6 µs / 38% — at 1 block/CU the phase barriers expose the
// LDS+stage path with no co-resident block to hide it. Reverted.)
template<bool OUT_BF16>
__global__ __launch_bounds__(256) void gemm_bt(const bf16* __restrict__ A, const bf16* __restrict__ Bt,
                                               void* __restrict__ C, int M, int N, int K) {
    __shared__ __align__(16) bf16 As[128 * 64];   // 16 KB
    __shared__ __align__(16) bf16 Bs[128 * 64];   // 16 KB
    const int tid = threadIdx.x;
    const int wave = tid >> 6, lane = tid & 63;
    const int l31 = lane & 31, half = lane >> 5;
    const int tile_n = blockIdx.x * 128, tile_m = blockIdx.y * 128;
    const int wm = (wave & 1) * 64, wn = (wave >> 1) * 64;
    const int sw = l31 & 7;                             // read-side swizzle
    f32x16 acc[2][2] = {};

    for (int k0 = 0; k0 < K; k0 += 64) {
        __syncthreads();
        #pragma unroll
        for (int j = 0; j < 4; ++j) {
            int s = j * 256 + tid;                       // LDS slot 0..1023 (16B each)
            int row = s >> 3, c = s & 7;
            int cs = c ^ (row & 7);                      // fetch permuted chunk
            GLOAD_LDS16(A  + (size_t)(tile_m + row) * K + k0 + (cs << 3), As + (size_t)s * 8);
            GLOAD_LDS16(Bt + (size_t)(tile_n + row) * K + k0 + (cs << 3), Bs + (size_t)s * 8);
        }
        __syncthreads();
        #pragma unroll
        for (int ks = 0; ks < 4; ++ks) {
            int ch = ((ks * 2 + half) ^ sw) << 3;
            bf16x8 a0 = *(const bf16x8*)(As + (size_t)(wm + l31) * 64 + ch);
            bf16x8 a1 = *(const bf16x8*)(As + (size_t)(wm + 32 + l31) * 64 + ch);
            bf16x8 b0 = *(const bf16x8*)(Bs + (size_t)(wn + l31) * 64 + ch);
            bf16x8 b1 = *(const bf16x8*)(Bs + (size_t)(wn + 32 + l31) * 64 + ch);
            acc[0][0] = __builtin_amdgcn_mfma_f32_32x32x16_bf16(a0, b0, acc[0][0], 0, 0, 0);
            acc[0][1] = __builtin_amdgcn_mfma_f32_32x32x16_bf16(a0, b1, acc[0][1], 0, 0, 0);
            acc[1][0] = __builtin_amdgcn_mfma_f32_32x32x16_bf16(a1, b0, acc[1][0], 0, 0, 0);
            acc[1][1] = __builtin_amdgcn_mfma_f32_32x32x16_bf16(a1, b1, acc[1][1], 0, 0, 0);
        }
    }
    // C/D layout (m74/m101): col = lane&31, row = (reg&3) + 8*(reg>>2) + 4*(lane>>5)
    #pragma unroll
    for (int mt = 0; mt < 2; ++mt)
        #pragma unroll
        for (int nt = 0; nt < 2; ++nt)
            #pragma unroll
            for (int reg = 0; reg < 16; ++reg) {
                int row = tile_m + wm + mt * 32 + (reg & 3) + ((reg >> 2) * 8) + half * 4;
                int col = tile_n + wn + nt * 32 + l31;
                float v = acc[mt][nt][reg];
                if (OUT_BF16) ((bf16*)C)[(size_t)row * N + col] = (bf16)v;
                else          ((float*)C)[(size_t)row * N + col] = v;
            }
}

// ---------------- fused post: per-head RMSNorm+RoPE (Q,K) + V transpose ----------------
__global__ __launch_bounds__(256) void post_kernel(const bf16* __restrict__ qkv,
                                                   const float* __restrict__ qnw, const float* __restrict__ knw,
                                                   const int* __restrict__ positions,
                                                   bf16* __restrict__ Qh, bf16* __restrict__ Kh,
                                                   bf16* __restrict__ VT) {
    int bx = blockIdx.x;
    if (bx < 4096) {
        int tk = bx;                      // token 0..4095
        int b = tk >> 11, s = tk & 2047;
        int wave = threadIdx.x >> 6, lane = threadIdx.x & 63;
        int e0 = lane * 2, e1 = e0 + 1;
        float pos = (float)positions[tk];
        const float L = 1.4533435415278355f;    // log2(theta)/16
        float a0 = pos * exp2f(-(float)(e0 & 15) * L);
        float a1 = pos * exp2f(-(float)(e1 & 15) * L);
        float cv0 = cosf(a0), sv0 = sinf(a0);
        float cv1 = cosf(a1), sv1 = sinf(a1);
        float qw0 = 1.0f + qnw[e0], qw1 = 1.0f + qnw[e1];
        float kw0 = 1.0f + knw[e0], kw1 = 1.0f + knw[e1];

        #pragma unroll
        for (int i = 0; i < 6; ++i) {
            // i<4: q heads {wave,wave+4,wave+8,wave+12}; i>=4: k heads {wave,wave+4}
            bool isq = (i < 4);
            int h = wave + (isq ? i : (i - 4)) * 4;
            const bf16* base = qkv + (size_t)tk * NQKV + (isq ? h * 256 : 4096 + h * HD);
            bf16x2 v = *(const bf16x2*)(base + e0);
            float f0 = (float)v[0], f1 = (float)v[1];
            float ssq = f0 * f0 + f1 * f1;
            #pragma unroll
            for (int off = 32; off; off >>= 1) ssq += __shfl_xor(ssq, off);
            float rn = rsqrtf(ssq * (1.0f / 128.0f) + 1e-6f);
            float w0 = isq ? qw0 : kw0, w1 = isq ? qw1 : kw1;
            float x0 = f0 * rn * w0, x1 = f1 * rn * w1;
            float p0 = __shfl_xor(x0, 8), p1 = __shfl_xor(x1, 8);
            float r0 = x0, r1 = x1;
            if (lane < 8)       { r0 = x0 * cv0 - p0 * sv0; r1 = x1 * cv1 - p1 * sv1; }
            else if (lane < 16) { r0 = p0 * sv0 + x0 * cv0; r1 = p1 * sv1 + x1 * cv1; }
            bf16x2 o; o[0] = (bf16)r0; o[1] = (bf16)r1;
            bf16* dst = isq ? (Qh + ((size_t)(b * NH + h) * SEQ + s) * HD)
                            : (Kh + ((size_t)(b * NKV + h) * SEQ + s) * HD);
            *(bf16x2*)(dst + e0) = o;
        }
    } else {
        int idx = bx - 4096;              // vtrans: 512 blocks
        int bh = idx >> 5, st = idx & 31;
        int b = bh >> 3, h = bh & 7;
        __shared__ float tile[64][129];
        int t = threadIdx.x;
        const bf16* src = qkv + ((size_t)(b * SEQ) + st * 64) * NQKV + 5120 + h * HD;
        #pragma unroll
        for (int i = 0; i < 32; ++i) {
            int ii = i * 256 + t;
            int tok = ii >> 7, d = ii & 127;
            tile[tok][d] = (float)src[(size_t)tok * NQKV + d];
        }
        __syncthreads();
        bf16* dst = VT + (size_t)(b * NKV + h) * HD * SEQ + st * 64;
        #pragma unroll
        for (int i = 0; i < 32; ++i) {
            int ii = i * 256 + t;
            int d = ii >> 6, sx = ii & 63;
            dst[(size_t)d * SEQ + sx] = (bf16)tile[sx][d];
        }
    }
}

// ---------------- flash attention, Br=128, Bc=64, 8 waves x 16 q-rows ----------------
// Round-4 change: 2-phase double-buffered K/V staging (T3-minimum + T14 issue-early).
// Old: {sync; stage(cur); sync[vmcnt(0) drain]; compute(cur)} — full staging latency
// exposed every K-tile, hidden only by the 1 other co-resident block.
// New: prologue stage(0); per-iter {__syncthreads(); stage(kt+1 -> buf^1); compute(buf)}
// — staging flies under the ~1200-cyc compute phase; one barrier/iter instead of two.
// Correctness: __syncthreads() is a full vmcnt(0)+lgkmcnt(0) fence (not a bare
// s_barrier — immune to the round-2 MFMA-sinking race): stage(kt) has landed at the
// top-of-iter fence, and buf^1's prior readers drained their lgkm before joining it.
// LDS: 2x(16K+16K) K/V + 16K Ps = 80 KB/block -> 2 blocks/CU = 160 KB exact fit.
__global__ __launch_bounds__(512, 4) void attn_kernel(const bf16* __restrict__ Qh, const bf16* __restrict__ Kh,
                                                      const bf16* __restrict__ VT, const bf16* __restrict__ qkv,
                                                      const int* __restrict__ amask, bf16* __restrict__ attnb) {
    const int bx = blockIdx.x;              // 512 blocks
    const int hb = (bx >> 4) & 31;          // b*16+head
    const int head = hb & 15, b = hb >> 4;
    int q0 = ((bx & 15) + hb) & 15;
    const int qt = (bx & 256) ? (15 - q0) : q0;   // pair sums constant work
    const int kvh = head >> 1;
    __shared__ __align__(16) bf16 Ks[2][64 * 128];  // [buf][row][chunk ^ (row&15)]
    __shared__ __align__(16) bf16 Vs[2][128 * 64];  // [buf][d][chunk ^ (d&7)]
    __shared__ __align__(16) bf16 Ps[8 * 16 * 64];  // per-wave, col ^ ((row>>2)*16)
    const int tid = threadIdx.x, wave = tid >> 6, lane = tid & 63;
    const int quad = lane >> 4, cl = lane & 15;

    // Q fragments in registers: rows qt*128 + wave*16 + cl
    const bf16* qsrc = Qh + ((size_t)(b * NH + head) * SEQ + qt * 128) * HD;
    bf16x8 aq[4];
    #pragma unroll
    for (int kc = 0; kc < 4; ++kc)
        aq[kc] = *(const bf16x8*)(qsrc + (size_t)(wave * 16 + cl) * HD + kc * 32 + quad * 8);

    float lstate[4] = {0.0f, 0.0f, 0.0f, 0.0f};
    f32x4 oacc[8] = {};
    const int qrow_glob = qt * 128 + wave * 16 + quad * 4;  // + r
    // exp2-domain: scale = (1/sqrt(128)) * log2(e); fixed max M = 20
    const float scale = 0.08838834764831845f * 1.4426950408889634f;
    const float M = 20.0f;
    const int kmax = 2 * qt + 1;

    const bf16* kbase = Kh + (size_t)(b * NKV + kvh) * SEQ * HD;
    const bf16* vbase = VT + (size_t)(b * NKV + kvh) * HD * SEQ;

#define STAGE_KV(kt_, buf_) { \
    const bf16* ksrc = kbase + (size_t)(kt_) * 64 * HD; \
    const bf16* vsrc = vbase + (size_t)(kt_) * 64; \
    _Pragma("unroll") \
    for (int j = 0; j < 2; ++j) { \
        int s = j * 512 + tid;                    /* 16B-chunk slot 0..1023 */ \
        int rK = s >> 4, cK = s & 15; \
        GLOAD_LDS16(ksrc + (size_t)rK * HD + ((cK ^ (rK & 15)) << 3), &Ks[buf_][0] + (size_t)s * 8); \
        int dV = s >> 3, cV = s & 7; \
        GLOAD_LDS16(vsrc + (size_t)dV * SEQ + ((cV ^ (dV & 7)) << 3), &Vs[buf_][0] + (size_t)s * 8); \
    } }

    STAGE_KV(0, 0);
    int cur = 0;
    for (int kt = 0; kt <= kmax; ++kt) {
        __syncthreads();                          // stage(kt) landed; buf^1 readers drained
        if (kt < kmax) STAGE_KV(kt + 1, cur ^ 1); // fly next tile under this tile's compute

        f32x4 sc[4] = {};
        #pragma unroll
        for (int nt = 0; nt < 4; ++nt)
            #pragma unroll
            for (int kc = 0; kc < 4; ++kc) {
                bf16x8 bk = *(const bf16x8*)(&Ks[cur][0] + (size_t)(nt * 16 + cl) * 128 + (((kc * 4 + quad) ^ cl) << 3));
                sc[nt] = __builtin_amdgcn_mfma_f32_16x16x32_bf16(aq[kc], bk, sc[nt], 0, 0, 0);
            }

        #pragma unroll
        for (int nt = 0; nt < 4; ++nt) {
            int kcol = kt * 64 + nt * 16 + cl;
            bool cok = (amask[b * SEQ + kcol] != 0);
            #pragma unroll
            for (int r = 0; r < 4; ++r) {
                bool ok = cok && (kcol <= qrow_glob + r);
                float p = ok ? exp2f(sc[nt][r] * scale - M) : 0.0f;
                lstate[r] += p;
                Ps[wave * 1024 + (quad * 4 + r) * 64 + ((nt * 16 + cl) ^ (quad << 4))] = (bf16)p;
            }
        }

        bf16x8 ap[2];
        #pragma unroll
        for (int c = 0; c < 2; ++c)
            ap[c] = *(const bf16x8*)(Ps + wave * 1024 + cl * 64 + ((c * 32 + quad * 8) ^ ((cl >> 2) << 4)));
        #pragma unroll
        for (int n2 = 0; n2 < 8; ++n2)
            #pragma unroll
            for (int c = 0; c < 2; ++c) {
                bf16x8 bv = *(const bf16x8*)(&Vs[cur][0] + (size_t)(n2 * 16 + cl) * 64 + (((c * 4 + quad) ^ (cl & 7)) << 3));
                oacc[n2] = __builtin_amdgcn_mfma_f32_16x16x32_bf16(ap[c], bv, oacc[n2], 0, 0, 0);
            }
        cur ^= 1;
    }
#undef STAGE_KV

    // epilogue: reduce l across the 16 col-lanes once, O/l, sigmoid gate, store
    #pragma unroll
    for (int r = 0; r < 4; ++r) {
        #pragma unroll
        for (int off = 8; off; off >>= 1) lstate[r] += __shfl_xor(lstate[r], off);
        int srow = qt * 128 + wave * 16 + quad * 4 + r;
        float linv = 1.0f / lstate[r];
        #pragma unroll
        for (int n2 = 0; n2 < 8; ++n2) {
            int d = n2 * 16 + cl;
            float g = (float)qkv[(size_t)(b * SEQ + srow) * NQKV + head * 256 + 128 + d];
            float sig = 1.0f / (1.0f + __expf(-g));
            float v = oacc[n2][r] * linv * sig;
            attnb[(size_t)(b * SEQ + srow) * HID + head * HD + d] = (bf16)v;
        }
    }
}

// ---------------- launch ----------------
extern "C" void kernel_launch(void* const* d_in, const int* in_sizes, int n_in,
                              void* d_out, int out_size, void* d_ws, size_t ws_size,
                              hipStream_t stream) {
    const float* x        = (const float*)d_in[0];
    const int*   amask    = (const int*)d_in[1];
    const int*   positions= (const int*)d_in[2];
    const float* Wq       = (const float*)d_in[3];
    const float* Wk       = (const float*)d_in[4];
    const float* Wv       = (const float*)d_in[5];
    const float* Wo       = (const float*)d_in[6];
    const float* qnw      = (const float*)d_in[7];
    const float* knw      = (const float*)d_in[8];
    float* out = (float*)d_out;
    char* ws = (char*)d_ws;

    bf16* xb    = (bf16*)(ws);                         // 16,777,216 B
    bf16* wqkvT = (bf16*)(ws + 16777216);              // 25,165,824 B
    bf16* woT   = (bf16*)(ws + 41943040);              //  8,388,608 B
    bf16* qkv   = (bf16*)(ws + 50331648);              // 50,331,648 B
    bf16* Qh    = (bf16*)(ws + 100663296);             // 16,777,216 B
    bf16* Kh    = (bf16*)(ws + 117440512);             //  8,388,608 B
    bf16* VT    = (bf16*)(ws + 125829120);             //  8,388,608 B
    bf16* attnb = (bf16*)(ws + 134217728);             // 16,777,216 B -> 150,994,944 total

    prep_kernel<<<12288, 256, 0, stream>>>(x, xb, Wq, Wk, Wv, Wo, wqkvT, woT);
    gemm_bt<true><<<dim3(48, 32), 256, 0, stream>>>(xb, wqkvT, qkv, MTOT, NQKV, HID);
    post_kernel<<<4608, 256, 0, stream>>>(qkv, qnw, knw, positions, Qh, Kh, VT);
    attn_kernel<<<512, 512, 0, stream>>>(Qh, Kh, VT, qkv, amask, attnb);
    gemm_bt<false><<<dim3(16, 32), 256, 0, stream>>>(attnb, woT, out, MTOT, HID, HID);

    (void)in_sizes; (void)n_in; (void)out_size; (void)ws_size;
}